// Round 9
// baseline (151.294 us; speedup 1.0000x reference)
//
#include <hip/hip_runtime.h>
#include <math.h>

#define MM 64
#define NA 24
#define NP 276
#define NT 6000
#define NTP 6048   // wT/eT rows padded to 63*96 (tail zeroed)
#define QC 0.22360679774997896f
#define EXPC 0.01666666666666667f  // 5/(3*sig^2), sig=10

// ws layout (float offsets)
#define OFF_XST  0        // xsT[p][m] 276*64
#define OFF_UU   17664    // 64
#define OFF_ES   17728    // 64  (zeroed)
#define OFF_SW   17792    // 64  (zeroed)
#define OFF_SH   17856    // 16 shadow arrays [276][64] (zeroed): idx (sh*2+mat)
#define OFF_WT   300480   // wT[t][m] NTP*64
#define OFF_ET   687552   // eT[t][m] NTP*64
#define ZTOT     282752   // ES+SW+SH

__device__ __forceinline__ float f4c(const float4& v, int i) {
  return i == 0 ? v.x : i == 1 ? v.y : i == 2 ? v.z : v.w;
}

// ---------- kernel 1: zero accum + tails; xsT[p][m] + uu ----------
__global__ __launch_bounds__(256) void k_pre(const float* __restrict__ Rs,
                                             float* __restrict__ ws) {
  const int tid = threadIdx.x;
  for (int z = blockIdx.x * 256 + tid; z < ZTOT; z += gridDim.x * 256)
    ws[OFF_ES + z] = 0.f;
  for (int z = blockIdx.x * 256 + tid; z < 6144; z += gridDim.x * 256) {
    if (z < 3072) ws[OFF_WT + 384000 + z] = 0.f;
    else          ws[OFF_ET + 384000 + (z - 3072)] = 0.f;
  }
  if (blockIdx.x < MM) {
    const int m = blockIdx.x;
    __shared__ float sR[NA * 3];
    __shared__ float sAcc[4];
    if (tid < NA * 3) sR[tid] = Rs[m * NA * 3 + tid];
    __syncthreads();
    float acc = 0.f;
    for (int p = tid; p < NP; p += 256) {
      int i = (int)((1.0f + sqrtf(1.0f + 8.0f * (float)p)) * 0.5f);
      while (i * (i - 1) / 2 > p) i--;
      while ((i + 1) * i / 2 <= p) i++;
      int j = p - i * (i - 1) / 2;
      float dx = sR[i * 3 + 0] - sR[j * 3 + 0];
      float dy = sR[i * 3 + 1] - sR[j * 3 + 1];
      float dz = sR[i * 3 + 2] - sR[j * 3 + 2];
      float u = 1.0f / sqrtf(dx * dx + dy * dy + dz * dz);
      ws[OFF_XST + p * 64 + m] = u;
      acc += u * u;
    }
    for (int off = 32; off; off >>= 1) acc += __shfl_down(acc, off);
    if ((tid & 63) == 0) sAcc[tid >> 6] = acc;
    __syncthreads();
    if (tid == 0) ws[OFF_UU + m] = sAcc[0] + sAcc[1] + sAcc[2] + sAcc[3];
  }
}

// ---------- kernel 2: fused GEMM1 + stats + elementwise ----------
// grid (375 t-tiles, 2 m-halves); block 256 = tile 32m x 16t.
// wave-lane: mg = lane&7 (4m each), tg = lane>>3 (2t each); ks = wave (K/4 split).
// Hot loop per 2k: 4x ds_read_b128 : 32 FMA  -> VALU-bound.
#define G1_BS 278   // Bs float2 row stride: 2-way-free banks, 16B-aligned
__global__ __launch_bounds__(256, 2) void k_g1(const float* __restrict__ xt,
                                               const float* __restrict__ Ja,
                                               float* __restrict__ ws) {
  __shared__ __align__(16) float2 Bs[16][G1_BS];
  __shared__ __align__(16) float As[NP][36];
  __shared__ float sVV[16], sC1[16];
  __shared__ __align__(16) float sRed[4][64][4];
  const int tid = threadIdx.x;
  const int t0 = blockIdx.x * 16;
  const int m0 = blockIdx.y * 32;
  const int lane = tid & 63;
  const int ks = tid >> 6;
  const int mg = lane & 7;
  const int tg = lane >> 3;

  // stage B: 16 t-rows x 69 quads of (xt,Ja) interleaved (v,j)
  for (int idx = tid; idx < 16 * 69; idx += 256) {
    const int row = idx / 69;
    const int kq = (idx - row * 69) * 4;
    const float4 v = *(const float4*)(xt + (size_t)(t0 + row) * NP + kq);
    const float4 j = *(const float4*)(Ja + (size_t)(t0 + row) * NP + kq);
    *(float4*)&Bs[row][kq]     = make_float4(v.x, j.x, v.y, j.y);
    *(float4*)&Bs[row][kq + 2] = make_float4(v.z, j.z, v.w, j.w);
  }
  // stage A: xs half-tile transposed [p][m-local] from xsT (L2-hot)
  for (int idx = tid; idx < NP * 8; idx += 256) {
    const int p = idx >> 3;
    const int mq = (idx & 7) * 4;
    *(float4*)&As[p][mq] = *(const float4*)(ws + OFF_XST + p * 64 + m0 + mq);
  }
  const float4 uu4 = *(const float4*)(ws + OFF_UU + m0 + mg * 4);
  __syncthreads();

  // in-block stats vv/c1 from staged Bs
  {
    const int tl = tid >> 4;
    const int l16 = tid & 15;
    float a = 0.f, b = 0.f;
    for (int k = l16; k < NP; k += 16) {
      const float2 x = Bs[tl][k];
      a = fmaf(x.x, x.x, a);
      b = fmaf(x.x, x.y, b);
    }
#pragma unroll
    for (int off = 8; off; off >>= 1) {
      a += __shfl_down(a, off, 16);
      b += __shfl_down(b, off, 16);
    }
    if (l16 == 0) { sVV[tl] = a; sC1[tl] = b; }
  }
  __syncthreads();

  float accv[2][4] = {{0.f,0.f,0.f,0.f},{0.f,0.f,0.f,0.f}};
  float accj[2][4] = {{0.f,0.f,0.f,0.f},{0.f,0.f,0.f,0.f}};
  const int kbeg = 70 * ks;
  const int kend = (ks == 3) ? NP : kbeg + 70;
#pragma unroll 5
  for (int k = kbeg; k < kend; k += 2) {
    const float4 bA = *(const float4*)&Bs[2 * tg][k];      // (v_k,j_k,v_k1,j_k1)
    const float4 bB = *(const float4*)&Bs[2 * tg + 1][k];
    const float4 a0 = *(const float4*)&As[k][mg * 4];
    const float4 a1 = *(const float4*)&As[k + 1][mg * 4];
#pragma unroll
    for (int i = 0; i < 4; i++) {
      const float x0 = f4c(a0, i), x1 = f4c(a1, i);
      accv[0][i] = fmaf(x0, bA.x, accv[0][i]); accj[0][i] = fmaf(x0, bA.y, accj[0][i]);
      accv[0][i] = fmaf(x1, bA.z, accv[0][i]); accj[0][i] = fmaf(x1, bA.w, accj[0][i]);
      accv[1][i] = fmaf(x0, bB.x, accv[1][i]); accj[1][i] = fmaf(x0, bB.y, accj[1][i]);
      accv[1][i] = fmaf(x1, bB.z, accv[1][i]); accj[1][i] = fmaf(x1, bB.w, accj[1][i]);
    }
  }

  // cross-wave K-split reduction, 4 passes through 4KB sRed
#pragma unroll
  for (int ps = 0; ps < 4; ps++) {
    __syncthreads();
    float4 v;
    if (ps == 0) v = make_float4(accv[0][0], accv[0][1], accv[0][2], accv[0][3]);
    else if (ps == 1) v = make_float4(accv[1][0], accv[1][1], accv[1][2], accv[1][3]);
    else if (ps == 2) v = make_float4(accj[0][0], accj[0][1], accj[0][2], accj[0][3]);
    else v = make_float4(accj[1][0], accj[1][1], accj[1][2], accj[1][3]);
    *(float4*)&sRed[ks][lane][0] = v;
    __syncthreads();
    if (ks == 0) {
      const float4 s0 = *(const float4*)&sRed[0][lane][0];
      const float4 s1 = *(const float4*)&sRed[1][lane][0];
      const float4 s2 = *(const float4*)&sRed[2][lane][0];
      const float4 s3 = *(const float4*)&sRed[3][lane][0];
      const float4 s = make_float4(s0.x + s1.x + s2.x + s3.x, s0.y + s1.y + s2.y + s3.y,
                                   s0.z + s1.z + s2.z + s3.z, s0.w + s1.w + s2.w + s3.w);
      if (ps == 0)      { accv[0][0]=s.x; accv[0][1]=s.y; accv[0][2]=s.z; accv[0][3]=s.w; }
      else if (ps == 1) { accv[1][0]=s.x; accv[1][1]=s.y; accv[1][2]=s.z; accv[1][3]=s.w; }
      else if (ps == 2) { accj[0][0]=s.x; accj[0][1]=s.y; accj[0][2]=s.z; accj[0][3]=s.w; }
      else              { accj[1][0]=s.x; accj[1][1]=s.y; accj[1][2]=s.z; accj[1][3]=s.w; }
    }
  }

  // epilogue on wave 0 only (holds full-K sums)
  if (ks == 0) {
    float es4[4] = {0.f,0.f,0.f,0.f}, sw4[4] = {0.f,0.f,0.f,0.f};
#pragma unroll
    for (int tt = 0; tt < 2; tt++) {
      const int t = t0 + tg * 2 + tt;
      const float vvt = sVV[tg * 2 + tt];
      const float c1t = sC1[tg * 2 + tt];
      float wq[4], eq[4];
#pragma unroll
      for (int i = 0; i < 4; i++) {
        float d2 = fmaxf(f4c(uu4, i) - 2.f * accv[tt][i] + vvt, 0.f);
        float xd = QC * sqrtf(d2);
        float dv = QC * (accj[tt][i] - c1t);
        float ex = EXPC * __expf(-xd);
        float e1v = ex * (1.f + xd);
        float w_ = ex * dv;
        wq[i] = w_; eq[i] = e1v;
        es4[i] += e1v * dv;
        sw4[i] += w_;
      }
      *(float4*)(ws + OFF_WT + (size_t)t * 64 + m0 + mg * 4) =
          make_float4(wq[0], wq[1], wq[2], wq[3]);
      *(float4*)(ws + OFF_ET + (size_t)t * 64 + m0 + mg * 4) =
          make_float4(eq[0], eq[1], eq[2], eq[3]);
    }
#pragma unroll
    for (int off = 8; off <= 32; off <<= 1) {
#pragma unroll
      for (int i = 0; i < 4; i++) {
        es4[i] += __shfl_down(es4[i], off);
        sw4[i] += __shfl_down(sw4[i], off);
      }
    }
    if (tg == 0) {
#pragma unroll
      for (int i = 0; i < 4; i++) {
        atomicAdd(ws + OFF_ES + m0 + mg * 4 + i, es4[i]);
        atomicAdd(ws + OFF_SW + m0 + mg * 4 + i, sw4[i]);
      }
    }
  }
}

// ---------- kernel 3: GEMM2 partials, thread = 4m x 4p, K-split 4, shadow atomics ----------
// grid (18 p-tiles x 63 k-chunks of 96); block 256 = tile 64m x 16p.
#define G2_KC 96
__global__ __launch_bounds__(256, 2) void k_g2(const float* __restrict__ xt,
                                               const float* __restrict__ Ja,
                                               float* __restrict__ ws) {
  __shared__ __align__(16) float Aw[G2_KC][68];
  __shared__ __align__(16) float Ae[G2_KC][68];
  __shared__ __align__(16) float2 Bvj[G2_KC][18];
  __shared__ __align__(16) float sRed[4][64][8];  // also reused as redP[32][64]
  const int tid = threadIdx.x;
  const int p0 = blockIdx.x * 16;
  const int k0 = blockIdx.y * G2_KC;
  const int validp = (NP - p0 < 16) ? (NP - p0) : 16;
  const int lane = tid & 63;
  const int ks = tid >> 6;
  const int mg = lane & 15;
  const int pg = lane >> 4;

  // stage A: wT/eT rows k0..k0+95 (rows >= NT zero-padded in ws)
  for (int idx = tid; idx < G2_KC * 16; idx += 256) {
    const int k = idx >> 4;
    const int mq = (idx & 15) * 4;
    *(float4*)&Aw[k][mq] = *(const float4*)(ws + OFF_WT + (size_t)(k0 + k) * 64 + mq);
    *(float4*)&Ae[k][mq] = *(const float4*)(ws + OFF_ET + (size_t)(k0 + k) * 64 + mq);
  }
  // stage B: (xt,Ja) interleaved [k][p-local]
  for (int idx = tid; idx < G2_KC * 4; idx += 256) {
    const int k = idx >> 2;
    const int pq = (idx & 3) * 4;
    const int t = k0 + k;
    float4 v = make_float4(0.f, 0.f, 0.f, 0.f), j = v;
    if (pq < validp && t < NT) {
      v = *(const float4*)(xt + (size_t)t * NP + p0 + pq);
      j = *(const float4*)(Ja + (size_t)t * NP + p0 + pq);
    }
    *(float4*)&Bvj[k][pq]     = make_float4(v.x, j.x, v.y, j.y);
    *(float4*)&Bvj[k][pq + 2] = make_float4(v.z, j.z, v.w, j.w);
  }
  __syncthreads();

  float f1[4][4] = {{0}}, f2[4][4] = {{0}};  // [m][p]
  const int kb = ks * 24;
#pragma unroll 4
  for (int k = kb; k < kb + 24; k++) {
    const float4 aw = *(const float4*)&Aw[k][mg * 4];
    const float4 ae = *(const float4*)&Ae[k][mg * 4];
    const float4 b0 = *(const float4*)&Bvj[k][pg * 4];      // (v,j,v,j) p,p+1
    const float4 b1 = *(const float4*)&Bvj[k][pg * 4 + 2];  // p+2,p+3
#pragma unroll
    for (int i = 0; i < 4; i++) {
      const float w_ = f4c(aw, i), e_ = f4c(ae, i);
      f1[i][0] = fmaf(w_, b0.x, f1[i][0]); f2[i][0] = fmaf(e_, b0.y, f2[i][0]);
      f1[i][1] = fmaf(w_, b0.z, f1[i][1]); f2[i][1] = fmaf(e_, b0.w, f2[i][1]);
      f1[i][2] = fmaf(w_, b1.x, f1[i][2]); f2[i][2] = fmaf(e_, b1.y, f2[i][2]);
      f1[i][3] = fmaf(w_, b1.z, f1[i][3]); f2[i][3] = fmaf(e_, b1.w, f2[i][3]);
    }
  }

  // cross-wave K-split reduction: 4 passes of 8 floats
#pragma unroll
  for (int ps = 0; ps < 4; ps++) {
    const int i0 = (ps & 1) * 2;
    float (*src)[4] = (ps < 2) ? f1 : f2;
    __syncthreads();
    *(float4*)&sRed[ks][lane][0] = make_float4(src[i0][0], src[i0][1], src[i0][2], src[i0][3]);
    *(float4*)&sRed[ks][lane][4] = make_float4(src[i0+1][0], src[i0+1][1], src[i0+1][2], src[i0+1][3]);
    __syncthreads();
    if (ks == 0) {
#pragma unroll
      for (int h = 0; h < 2; h++) {
        const float4 s0 = *(const float4*)&sRed[0][lane][4 * h];
        const float4 s1 = *(const float4*)&sRed[1][lane][4 * h];
        const float4 s2 = *(const float4*)&sRed[2][lane][4 * h];
        const float4 s3 = *(const float4*)&sRed[3][lane][4 * h];
        src[i0 + h][0] = s0.x + s1.x + s2.x + s3.x;
        src[i0 + h][1] = s0.y + s1.y + s2.y + s3.y;
        src[i0 + h][2] = s0.z + s1.z + s2.z + s3.z;
        src[i0 + h][3] = s0.w + s1.w + s2.w + s3.w;
      }
    }
  }

  // park full sums in [p][m] layout for a coalesced atomic phase
  float* redP = &sRed[0][0][0];  // [32][64]: rows 0..15 = mat1, 16..31 = mat2
  __syncthreads();
  if (ks == 0) {
#pragma unroll
    for (int j = 0; j < 4; j++) {
      const int pl = pg * 4 + j;
#pragma unroll
      for (int i = 0; i < 4; i++) {
        redP[pl * 64 + mg * 4 + i]        = f1[i][j];
        redP[(16 + pl) * 64 + mg * 4 + i] = f2[i][j];
      }
    }
  }
  __syncthreads();
  const int m = tid & 63;
  const int sh = blockIdx.y & 7;
  float* b1 = ws + OFF_SH + (size_t)(sh * 2 + 0) * NP * 64;
  float* b2 = ws + OFF_SH + (size_t)(sh * 2 + 1) * NP * 64;
#pragma unroll
  for (int q = 0; q < 4; q++) {
    const int pl = (tid >> 6) + q * 4;
    if (pl < validp) {
      const int p = p0 + pl;
      atomicAdd(b1 + (size_t)p * 64 + m, redP[pl * 64 + m]);
      atomicAdd(b2 + (size_t)p * 64 + m, redP[(16 + pl) * 64 + m]);
    }
  }
}

// ---------- kernel 4: finalize (reduce shadows, force gather, Es) ----------
__global__ __launch_bounds__(320) void k_final(const float* __restrict__ Rs,
                                               const float* __restrict__ ws,
                                               float* __restrict__ out) {
  const int m = blockIdx.x;
  const int tid = threadIdx.x;
  __shared__ float fx[NP];
  __shared__ float sR[NA * 3];
  if (tid < NA * 3) sR[tid] = Rs[m * NA * 3 + tid];
  const float sw = ws[OFF_SW + m];
  for (int p = tid; p < NP; p += 320) {
    float f1p = 0.f, f2 = 0.f;
#pragma unroll
    for (int s = 0; s < 8; s++) {
      f1p += ws[OFF_SH + ((size_t)(s * 2 + 0) * NP + p) * 64 + m];
      f2  += ws[OFF_SH + ((size_t)(s * 2 + 1) * NP + p) * 64 + m];
    }
    const float u = ws[OFF_XST + p * 64 + m];
    const float F1 = QC * (u * sw - f1p);
    fx[p] = (F1 - f2) * u * u * u;
  }
  __syncthreads();
  if (tid == 0) out[m] = ws[OFF_ES + m] / QC;  // *STD + C, STD=1, C=0
  if (tid < NA * 3) {
    const int a = tid / 3, cc = tid % 3;
    const float ra = sR[a * 3 + cc];
    float acc = 0.f;
    for (int b = 0; b < NA; b++) {
      if (b == a) continue;
      const int i = a > b ? a : b, j = a > b ? b : a;
      const int p = i * (i - 1) / 2 + j;
      acc += (sR[b * 3 + cc] - ra) * fx[p];
    }
    out[MM + m * NA * 3 + tid] = acc;
  }
}

extern "C" void kernel_launch(void* const* d_in, const int* in_sizes, int n_in,
                              void* d_out, int out_size, void* d_ws, size_t ws_size,
                              hipStream_t stream) {
  const float* Rs = (const float*)d_in[0];
  const float* xt = (const float*)d_in[1];
  const float* Ja = (const float*)d_in[2];
  float* out = (float*)d_out;
  float* ws = (float*)d_ws;

  k_pre<<<256, 256, 0, stream>>>(Rs, ws);
  k_g1<<<dim3(375, 2), 256, 0, stream>>>(xt, Ja, ws);
  k_g2<<<dim3(18, 63), 256, 0, stream>>>(xt, Ja, ws);
  k_final<<<MM, 320, 0, stream>>>(Rs, ws, out);
}

// Round 10
// 150.651 us; speedup vs baseline: 1.0043x; 1.0043x over previous
//
#include <hip/hip_runtime.h>
#include <math.h>

#define MM 64
#define NA 24
#define NP 276
#define NT 6000
#define NTP 6048   // wT/eT rows padded to 63*96 (tail zeroed)
#define QC 0.22360679774997896f
#define EXPC 0.01666666666666667f  // 5/(3*sig^2), sig=10

// ws layout (float offsets)
#define OFF_SH   0         // 16 shadow arrays [276][64] (zeroed by k_g1): idx (sh*2+mat)
#define OFF_PES  282624    // es partials [half][375][32] (fully written by k_g1)
#define OFF_PSW  306624    // sw partials [half][375][32]
#define OFF_WT   330624    // wT[t][m] NTP*64 (tail rows zeroed by k_g1)
#define OFF_ET   717696    // eT[t][m] NTP*64
// total 1,104,768 floats = 4.42 MB

__device__ __forceinline__ float f4c(const float4& v, int i) {
  return i == 0 ? v.x : i == 1 ? v.y : i == 2 ? v.z : v.w;
}

// ---------- kernel 1: fused zero + A-build + GEMM1 + stats + elementwise ----------
// grid (375 t-tiles, 2 m-halves); block 256 = tile 32m x 16t; thread = 2m x 1t.
// Hot loop (R8-verbatim): per 2k: 1x ds_read_b128 (Bs) + 2x ds_read_b64 (As) + 8 FMA.
// LDS plan (flat): Bs 16x278 float2 (8896 f) | As 276x34 (9384 f) | small tail.
// sR (32x73) overlays the Bs region during the A-build phase.
#define S_BS  0
#define S_AS  8896
#define S_VV  18280
#define S_C1  18296
#define S_UU  18312   // [8][32]
#define S_UUF 18568   // [32]
#define S_ESW 18600   // [4][32]
#define S_SWW 18728   // [4][32]
#define S_TOT 18856   // floats = 75.4 KB
__global__ __launch_bounds__(256, 2) void k_g1(const float* __restrict__ Rs,
                                               const float* __restrict__ xt,
                                               const float* __restrict__ Ja,
                                               float* __restrict__ ws) {
  __shared__ __align__(16) float smem[S_TOT];
  const int tid = threadIdx.x;
  const int t0 = blockIdx.x * 16;
  const int m0 = blockIdx.y * 32;

  // --- preamble: zero shadows + wT/eT tails (global, consumed only by later kernels)
  {
    const int gid = blockIdx.y * 375 + blockIdx.x;
    for (int z = gid * 256 + tid; z < 288768; z += 192000) {
      if (z < 282624)      ws[OFF_SH + z] = 0.f;
      else if (z < 285696) ws[OFF_WT + 384000 + (z - 282624)] = 0.f;
      else                 ws[OFF_ET + 384000 + (z - 285696)] = 0.f;
    }
  }

  // --- phase A: load Rs half into sR (stride 73, overlays Bs region)
  for (int idx = tid; idx < 32 * 72; idx += 256) {
    const int ml = idx / 72, q = idx - ml * 72;
    smem[S_BS + ml * 73 + q] = Rs[(size_t)(m0 + ml) * 72 + q];
  }
  __syncthreads();

  // --- phase B: build As[p][ml] = 1/dist, accumulate uu partials
  {
    const int ml = tid & 31;
    const float* sR = smem + S_BS + ml * 73;
    float uup = 0.f;
    for (int p = tid >> 5; p < NP; p += 8) {
      int i = (int)((1.0f + sqrtf(1.0f + 8.0f * (float)p)) * 0.5f);
      while (i * (i - 1) / 2 > p) i--;
      while ((i + 1) * i / 2 <= p) i++;
      const int j = p - i * (i - 1) / 2;
      const float dx = sR[i * 3 + 0] - sR[j * 3 + 0];
      const float dy = sR[i * 3 + 1] - sR[j * 3 + 1];
      const float dz = sR[i * 3 + 2] - sR[j * 3 + 2];
      const float u = 1.0f / sqrtf(dx * dx + dy * dy + dz * dz);
      smem[S_AS + p * 34 + ml] = u;
      uup = fmaf(u, u, uup);
    }
    smem[S_UU + (tid >> 5) * 32 + ml] = uup;
  }
  __syncthreads();
  if (tid < 32) {
    float s = 0.f;
#pragma unroll
    for (int k = 0; k < 8; k++) s += smem[S_UU + k * 32 + tid];
    smem[S_UUF + tid] = s;
  }
  __syncthreads();  // As + uu final; sR no longer needed

  // --- phase C: stage Bs = (xt,Ja) interleaved [t-local][k] (overwrites sR region)
  {
    float2* Bs = (float2*)(smem + S_BS);
    for (int idx = tid; idx < 16 * 69; idx += 256) {
      const int row = idx / 69;
      const int kq = (idx - row * 69) * 4;
      const float4 v = *(const float4*)(xt + (size_t)(t0 + row) * NP + kq);
      const float4 j = *(const float4*)(Ja + (size_t)(t0 + row) * NP + kq);
      *(float4*)&Bs[row * 278 + kq]     = make_float4(v.x, j.x, v.y, j.y);
      *(float4*)&Bs[row * 278 + kq + 2] = make_float4(v.z, j.z, v.w, j.w);
    }
  }
  __syncthreads();

  // --- phase D: in-block stats vv/c1 from staged Bs
  {
    const float2* Bs = (const float2*)(smem + S_BS);
    const int tl = tid >> 4;
    const int l16 = tid & 15;
    float a = 0.f, b = 0.f;
    for (int k = l16; k < NP; k += 16) {
      const float2 x = Bs[tl * 278 + k];
      a = fmaf(x.x, x.x, a);
      b = fmaf(x.x, x.y, b);
    }
#pragma unroll
    for (int off = 8; off; off >>= 1) {
      a += __shfl_down(a, off, 16);
      b += __shfl_down(b, off, 16);
    }
    if (l16 == 0) { smem[S_VV + tl] = a; smem[S_C1 + tl] = b; }
  }
  __syncthreads();

  // --- phase E: hot loop (R8 structure)
  const int r = tid & 15;   // m-pair: m = m0+2r, +1
  const int c = tid >> 4;   // t-column: t = t0+c
  float av0 = 0.f, av1 = 0.f, aj0 = 0.f, aj1 = 0.f;
  {
    const float2* Bs = (const float2*)(smem + S_BS);
#pragma unroll 4
    for (int kk = 0; kk < NP; kk += 2) {
      const float4 b  = *(const float4*)&Bs[c * 278 + kk];  // (v_k,j_k,v_k1,j_k1)
      const float2 a0 = *(const float2*)&smem[S_AS + kk * 34 + 2 * r];
      const float2 a1 = *(const float2*)&smem[S_AS + (kk + 1) * 34 + 2 * r];
      av0 = fmaf(a0.x, b.x, av0); aj0 = fmaf(a0.x, b.y, aj0);
      av1 = fmaf(a0.y, b.x, av1); aj1 = fmaf(a0.y, b.y, aj1);
      av0 = fmaf(a1.x, b.z, av0); aj0 = fmaf(a1.x, b.w, aj0);
      av1 = fmaf(a1.y, b.z, av1); aj1 = fmaf(a1.y, b.w, aj1);
    }
  }

  // --- phase F: elementwise epilogue
  const float vvt = smem[S_VV + c];
  const float c1t = smem[S_C1 + c];
  const float uum0 = smem[S_UUF + 2 * r];
  const float uum1 = smem[S_UUF + 2 * r + 1];
  float es2[2], sw2[2], wv[2], ev[2];
#pragma unroll
  for (int i = 0; i < 2; i++) {
    const float g1v = i ? av1 : av0;
    const float g2v = i ? aj1 : aj0;
    const float uum = i ? uum1 : uum0;
    float d2 = fmaxf(uum - 2.f * g1v + vvt, 0.f);
    float xd = QC * sqrtf(d2);
    float dv = QC * (g2v - c1t);
    float ex = EXPC * __expf(-xd);
    float e1v = ex * (1.f + xd);
    float w_ = ex * dv;
    wv[i] = w_; ev[i] = e1v;
    es2[i] = e1v * dv;
    sw2[i] = w_;
  }
  const int t = t0 + c;
  *(float2*)(ws + OFF_WT + (size_t)t * 64 + m0 + 2 * r) = make_float2(wv[0], wv[1]);
  *(float2*)(ws + OFF_ET + (size_t)t * 64 + m0 + 2 * r) = make_float2(ev[0], ev[1]);

  // reduce es/sw over the wave's 4 c-groups, then cross-wave, write block partials
#pragma unroll
  for (int i = 0; i < 2; i++) {
    es2[i] += __shfl_down(es2[i], 32); es2[i] += __shfl_down(es2[i], 16);
    sw2[i] += __shfl_down(sw2[i], 32); sw2[i] += __shfl_down(sw2[i], 16);
  }
  const int w = tid >> 6;
  if ((tid & 63) < 16) {
    smem[S_ESW + w * 32 + 2 * r + 0] = es2[0];
    smem[S_ESW + w * 32 + 2 * r + 1] = es2[1];
    smem[S_SWW + w * 32 + 2 * r + 0] = sw2[0];
    smem[S_SWW + w * 32 + 2 * r + 1] = sw2[1];
  }
  __syncthreads();
  if (tid < 32) {
    float es = 0.f, sw = 0.f;
#pragma unroll
    for (int k = 0; k < 4; k++) {
      es += smem[S_ESW + k * 32 + tid];
      sw += smem[S_SWW + k * 32 + tid];
    }
    ws[OFF_PES + (size_t)blockIdx.y * 375 * 32 + blockIdx.x * 32 + tid] = es;
    ws[OFF_PSW + (size_t)blockIdx.y * 375 * 32 + blockIdx.x * 32 + tid] = sw;
  }
}

// ---------- kernel 2: GEMM2 partials (R8-verbatim), shadow atomics ----------
// grid (18 p-tiles x 63 k-chunks of 96); block 256 = tile 64m x 16p; thread 2m x 2p.
#define G2_KC 96
__global__ __launch_bounds__(256, 2) void k_g2(const float* __restrict__ xt,
                                               const float* __restrict__ Ja,
                                               float* __restrict__ ws) {
  __shared__ __align__(16) float Aw[G2_KC][68];
  __shared__ __align__(16) float Ae[G2_KC][68];
  __shared__ __align__(16) float2 Bvj[G2_KC][18];
  const int tid = threadIdx.x;
  const int p0 = blockIdx.x * 16;
  const int k0 = blockIdx.y * G2_KC;
  const int validp = (NP - p0 < 16) ? (NP - p0) : 16;

  // stage A: wT/eT rows k0..k0+95 (rows >= NT zero-padded in ws)
  for (int idx = tid; idx < G2_KC * 16; idx += 256) {
    const int k = idx >> 4;
    const int mq = (idx & 15) * 4;
    *(float4*)&Aw[k][mq] = *(const float4*)(ws + OFF_WT + (size_t)(k0 + k) * 64 + mq);
    *(float4*)&Ae[k][mq] = *(const float4*)(ws + OFF_ET + (size_t)(k0 + k) * 64 + mq);
  }
  // stage B: (xt,Ja) interleaved [k][p-local]
  for (int idx = tid; idx < G2_KC * 4; idx += 256) {
    const int k = idx >> 2;
    const int pq = (idx & 3) * 4;
    const int t = k0 + k;
    float4 v = make_float4(0.f, 0.f, 0.f, 0.f), j = v;
    if (pq < validp && t < NT) {
      v = *(const float4*)(xt + (size_t)t * NP + p0 + pq);
      j = *(const float4*)(Ja + (size_t)t * NP + p0 + pq);
    }
    *(float4*)&Bvj[k][pq]     = make_float4(v.x, j.x, v.y, j.y);
    *(float4*)&Bvj[k][pq + 2] = make_float4(v.z, j.z, v.w, j.w);
  }
  __syncthreads();

  const int r = tid & 31;   // m-pair
  const int c = tid >> 5;   // p-pair
  float f1[2][2] = {{0.f, 0.f}, {0.f, 0.f}};  // [m][p]
  float f2[2][2] = {{0.f, 0.f}, {0.f, 0.f}};
#pragma unroll 4
  for (int k = 0; k < G2_KC; k++) {
    const float2 aw = *(const float2*)&Aw[k][2 * r];
    const float2 ae = *(const float2*)&Ae[k][2 * r];
    const float4 b  = *(const float4*)&Bvj[k][2 * c];  // (v_p, j_p, v_p1, j_p1)
    f1[0][0] = fmaf(aw.x, b.x, f1[0][0]); f1[0][1] = fmaf(aw.x, b.z, f1[0][1]);
    f1[1][0] = fmaf(aw.y, b.x, f1[1][0]); f1[1][1] = fmaf(aw.y, b.z, f1[1][1]);
    f2[0][0] = fmaf(ae.x, b.y, f2[0][0]); f2[0][1] = fmaf(ae.x, b.w, f2[0][1]);
    f2[1][0] = fmaf(ae.y, b.y, f2[1][0]); f2[1][1] = fmaf(ae.y, b.w, f2[1][1]);
  }

  const int sh = blockIdx.y & 7;
  float* b1 = ws + OFF_SH + (size_t)(sh * 2 + 0) * NP * 64;
  float* b2 = ws + OFF_SH + (size_t)(sh * 2 + 1) * NP * 64;
#pragma unroll
  for (int j = 0; j < 2; j++) {
    const int pl = 2 * c + j;
    if (pl < validp) {
      const int p = p0 + pl;
#pragma unroll
      for (int i = 0; i < 2; i++) {
        atomicAdd(b1 + (size_t)p * 64 + 2 * r + i, f1[i][j]);
        atomicAdd(b2 + (size_t)p * 64 + 2 * r + i, f2[i][j]);
      }
    }
  }
}

// ---------- kernel 3: finalize (reduce partials + shadows, force gather, Es) ----------
__global__ __launch_bounds__(320) void k_final(const float* __restrict__ Rs,
                                               const float* __restrict__ ws,
                                               float* __restrict__ out) {
  const int m = blockIdx.x;
  const int tid = threadIdx.x;
  __shared__ float fx[NP];
  __shared__ float sR[NA * 3];
  __shared__ float sE[5], sW[5], sFin[2];
  if (tid < NA * 3) sR[tid] = Rs[(size_t)m * 72 + tid];

  // reduce es/sw partials (375 blocks x m-half layout)
  {
    const int half = m >> 5, ml = m & 31;
    float esp = 0.f, swp = 0.f;
    for (int b = tid; b < 375; b += 320) {
      esp += ws[OFF_PES + (size_t)half * 375 * 32 + b * 32 + ml];
      swp += ws[OFF_PSW + (size_t)half * 375 * 32 + b * 32 + ml];
    }
#pragma unroll
    for (int off = 32; off; off >>= 1) {
      esp += __shfl_down(esp, off);
      swp += __shfl_down(swp, off);
    }
    if ((tid & 63) == 0) { sE[tid >> 6] = esp; sW[tid >> 6] = swp; }
  }
  __syncthreads();
  if (tid == 0) {
    float es = 0.f, sw = 0.f;
#pragma unroll
    for (int k = 0; k < 5; k++) { es += sE[k]; sw += sW[k]; }
    sFin[0] = es; sFin[1] = sw;
  }
  __syncthreads();
  const float sw = sFin[1];

  if (tid < NP) {
    const int p = tid;
    int i = (int)((1.0f + sqrtf(1.0f + 8.0f * (float)p)) * 0.5f);
    while (i * (i - 1) / 2 > p) i--;
    while ((i + 1) * i / 2 <= p) i++;
    const int j = p - i * (i - 1) / 2;
    const float dx = sR[i * 3 + 0] - sR[j * 3 + 0];
    const float dy = sR[i * 3 + 1] - sR[j * 3 + 1];
    const float dz = sR[i * 3 + 2] - sR[j * 3 + 2];
    const float u = 1.0f / sqrtf(dx * dx + dy * dy + dz * dz);
    float f1p = 0.f, f2 = 0.f;
#pragma unroll
    for (int s = 0; s < 8; s++) {
      f1p += ws[OFF_SH + ((size_t)(s * 2 + 0) * NP + p) * 64 + m];
      f2  += ws[OFF_SH + ((size_t)(s * 2 + 1) * NP + p) * 64 + m];
    }
    const float F1 = QC * (u * sw - f1p);
    fx[p] = (F1 - f2) * u * u * u;
  }
  __syncthreads();
  if (tid == 0) out[m] = sFin[0] / QC;  // *STD + C, STD=1, C=0
  if (tid < NA * 3) {
    const int a = tid / 3, cc = tid % 3;
    const float ra = sR[a * 3 + cc];
    float acc = 0.f;
    for (int b = 0; b < NA; b++) {
      if (b == a) continue;
      const int i = a > b ? a : b, j = a > b ? b : a;
      const int p = i * (i - 1) / 2 + j;
      acc += (sR[b * 3 + cc] - ra) * fx[p];
    }
    out[MM + (size_t)m * NA * 3 + tid] = acc;
  }
}

extern "C" void kernel_launch(void* const* d_in, const int* in_sizes, int n_in,
                              void* d_out, int out_size, void* d_ws, size_t ws_size,
                              hipStream_t stream) {
  const float* Rs = (const float*)d_in[0];
  const float* xt = (const float*)d_in[1];
  const float* Ja = (const float*)d_in[2];
  float* out = (float*)d_out;
  float* ws = (float*)d_ws;

  k_g1<<<dim3(375, 2), 256, 0, stream>>>(Rs, xt, Ja, ws);
  k_g2<<<dim3(18, 63), 256, 0, stream>>>(xt, Ja, ws);
  k_final<<<MM, 320, 0, stream>>>(Rs, ws, out);
}

// Round 11
// 137.097 us; speedup vs baseline: 1.1036x; 1.0989x over previous
//
#include <hip/hip_runtime.h>
#include <math.h>

#define MM 64
#define NA 24
#define NP 276
#define NT 6000
#define NTP 6048   // wT/eT rows padded to 63*96 (tail zeroed)
#define QC 0.22360679774997896f
#define EXPC 0.01666666666666667f  // 5/(3*sig^2), sig=10

// ws layout (float offsets) -- R8 map (VV/C1 slots retired)
#define OFF_XST  0        // xsT[p][m] 276*64
#define OFF_UU   17664    // 64
#define OFF_ES   17728    // 64  (zeroed)
#define OFF_SW   17792    // 64  (zeroed)
#define OFF_SH   17856    // 16 shadow arrays [276][64] (zeroed): idx (sh*2+mat)
#define OFF_WT   300480   // wT[t][m] NTP*64
#define OFF_ET   687552   // eT[t][m] NTP*64
#define ZTOT     282752   // ES+SW+SH

__device__ __forceinline__ float f4c(const float4& v, int i) {
  return i == 0 ? v.x : i == 1 ? v.y : i == 2 ? v.z : v.w;
}

// ---------- kernel 1: zero accum + tails; xsT[p][m] + uu (no stats pass) ----------
__global__ __launch_bounds__(256) void k_pre(const float* __restrict__ Rs,
                                             float* __restrict__ ws) {
  const int tid = threadIdx.x;
  for (int z = blockIdx.x * 256 + tid; z < ZTOT; z += gridDim.x * 256)
    ws[OFF_ES + z] = 0.f;
  for (int z = blockIdx.x * 256 + tid; z < 6144; z += gridDim.x * 256) {
    if (z < 3072) ws[OFF_WT + 384000 + z] = 0.f;
    else          ws[OFF_ET + 384000 + (z - 3072)] = 0.f;
  }
  if (blockIdx.x < MM) {
    const int m = blockIdx.x;
    __shared__ float sR[NA * 3];
    __shared__ float sAcc[4];
    if (tid < NA * 3) sR[tid] = Rs[m * NA * 3 + tid];
    __syncthreads();
    float acc = 0.f;
    for (int p = tid; p < NP; p += 256) {
      int i = (int)((1.0f + sqrtf(1.0f + 8.0f * (float)p)) * 0.5f);
      while (i * (i - 1) / 2 > p) i--;
      while ((i + 1) * i / 2 <= p) i++;
      int j = p - i * (i - 1) / 2;
      float dx = sR[i * 3 + 0] - sR[j * 3 + 0];
      float dy = sR[i * 3 + 1] - sR[j * 3 + 1];
      float dz = sR[i * 3 + 2] - sR[j * 3 + 2];
      float u = 1.0f / sqrtf(dx * dx + dy * dy + dz * dz);
      ws[OFF_XST + p * 64 + m] = u;
      acc += u * u;
    }
    for (int off = 32; off; off >>= 1) acc += __shfl_down(acc, off);
    if ((tid & 63) == 0) sAcc[tid >> 6] = acc;
    __syncthreads();
    if (tid == 0) ws[OFF_UU + m] = sAcc[0] + sAcc[1] + sAcc[2] + sAcc[3];
  }
}

// ---------- kernel 2: fused GEMM1 + in-block stats + elementwise (R8 hot loop) ----------
// grid (375 t-tiles, 2 m-halves); block 256 = tile 32m x 16t; thread = 2m x 1t.
#define G1_BS 280  // float2 per t-row
#define G1_AS 36   // As row stride (floats), mult of 4
__global__ __launch_bounds__(256, 2) void k_g1(const float* __restrict__ xt,
                                               const float* __restrict__ Ja,
                                               float* __restrict__ ws) {
  __shared__ __align__(16) float2 Bs[16][G1_BS];
  __shared__ __align__(16) float As[NP][G1_AS];
  __shared__ float sVV[16], sC1[16];
  __shared__ float sEsW[4][32], sSwW[4][32];
  const int tid = threadIdx.x;
  const int t0 = blockIdx.x * 16;
  const int m0 = blockIdx.y * 32;

  // stage B: 16 t-rows x 69 float4-quads of xt & Ja, interleaved (v,j)
  for (int idx = tid; idx < 16 * 69; idx += 256) {
    const int row = idx / 69;
    const int kq = (idx - row * 69) * 4;
    const float4 v = *(const float4*)(xt + (size_t)(t0 + row) * NP + kq);
    const float4 j = *(const float4*)(Ja + (size_t)(t0 + row) * NP + kq);
    *(float4*)&Bs[row][kq]     = make_float4(v.x, j.x, v.y, j.y);
    *(float4*)&Bs[row][kq + 2] = make_float4(v.z, j.z, v.w, j.w);
  }
  // stage A: 276 p-rows x 8 m-quads from xsT (L2-hot)
  for (int idx = tid; idx < NP * 8; idx += 256) {
    const int p = idx >> 3;
    const int mq = (idx & 7) * 4;
    *(float4*)&As[p][mq] = *(const float4*)(ws + OFF_XST + p * 64 + m0 + mq);
  }
  const int r = tid & 15;   // m-pair
  const int c = tid >> 4;   // t-column
  const float2 uu2 = *(const float2*)(ws + OFF_UU + m0 + 2 * r);
  __syncthreads();

  // in-block stats: vv[t], c1[t] from staged Bs (R10-proven)
  {
    const int tl = tid >> 4;
    const int l16 = tid & 15;
    float a = 0.f, b = 0.f;
    for (int k = l16; k < NP; k += 16) {
      const float2 x = Bs[tl][k];
      a = fmaf(x.x, x.x, a);
      b = fmaf(x.x, x.y, b);
    }
#pragma unroll
    for (int off = 8; off; off >>= 1) {
      a += __shfl_down(a, off, 16);
      b += __shfl_down(b, off, 16);
    }
    if (l16 == 0) { sVV[tl] = a; sC1[tl] = b; }
  }
  __syncthreads();

  float av0 = 0.f, av1 = 0.f, aj0 = 0.f, aj1 = 0.f;
#pragma unroll 4
  for (int kk = 0; kk < NP; kk += 2) {
    const float4 b  = *(const float4*)&Bs[c][kk];    // (v_k, j_k, v_k1, j_k1)
    const float2 a0 = *(const float2*)&As[kk][2 * r];
    const float2 a1 = *(const float2*)&As[kk + 1][2 * r];
    av0 = fmaf(a0.x, b.x, av0); aj0 = fmaf(a0.x, b.y, aj0);
    av1 = fmaf(a0.y, b.x, av1); aj1 = fmaf(a0.y, b.y, aj1);
    av0 = fmaf(a1.x, b.z, av0); aj0 = fmaf(a1.x, b.w, aj0);
    av1 = fmaf(a1.y, b.z, av1); aj1 = fmaf(a1.y, b.w, aj1);
  }

  // elementwise epilogue: t = t0+c, m = m0+2r+{0,1}
  const float vvt = sVV[c];
  const float c1t = sC1[c];
  float es2[2], sw2[2], wv[2], ev[2];
#pragma unroll
  for (int i = 0; i < 2; i++) {
    const float g1v = i ? av1 : av0;
    const float g2v = i ? aj1 : aj0;
    const float uum = i ? uu2.y : uu2.x;
    float d2 = fmaxf(uum - 2.f * g1v + vvt, 0.f);
    float xd = QC * sqrtf(d2);
    float dv = QC * (g2v - c1t);
    float ex = EXPC * __expf(-xd);
    float e1v = ex * (1.f + xd);
    float w_ = ex * dv;
    wv[i] = w_; ev[i] = e1v;
    es2[i] = e1v * dv;
    sw2[i] = w_;
  }
  const int t = t0 + c;
  *(float2*)(ws + OFF_WT + (size_t)t * 64 + m0 + 2 * r) = make_float2(wv[0], wv[1]);
  *(float2*)(ws + OFF_ET + (size_t)t * 64 + m0 + 2 * r) = make_float2(ev[0], ev[1]);

  // reduce es/sw over the wave's 4 c-groups, park per wave, then coalesced atomics
#pragma unroll
  for (int i = 0; i < 2; i++) {
    es2[i] += __shfl_down(es2[i], 32); es2[i] += __shfl_down(es2[i], 16);
    sw2[i] += __shfl_down(sw2[i], 32); sw2[i] += __shfl_down(sw2[i], 16);
  }
  const int w = tid >> 6;
  if ((tid & 63) < 16) {
    sEsW[w][2 * r + 0] = es2[0]; sEsW[w][2 * r + 1] = es2[1];
    sSwW[w][2 * r + 0] = sw2[0]; sSwW[w][2 * r + 1] = sw2[1];
  }
  __syncthreads();
  if (tid < 32) {
    const float es = sEsW[0][tid] + sEsW[1][tid] + sEsW[2][tid] + sEsW[3][tid];
    const float sw = sSwW[0][tid] + sSwW[1][tid] + sSwW[2][tid] + sSwW[3][tid];
    atomicAdd(ws + OFF_ES + m0 + tid, es);
    atomicAdd(ws + OFF_SW + m0 + tid, sw);
  }
}

// ---------- kernel 3: GEMM2 partials (R8-verbatim), shadow atomics ----------
// grid (18 p-tiles x 63 k-chunks of 96); block 256 = tile 64m x 16p.
#define G2_KC 96
__global__ __launch_bounds__(256, 2) void k_g2(const float* __restrict__ xt,
                                               const float* __restrict__ Ja,
                                               float* __restrict__ ws) {
  __shared__ __align__(16) float Aw[G2_KC][68];
  __shared__ __align__(16) float Ae[G2_KC][68];
  __shared__ __align__(16) float2 Bvj[G2_KC][18];
  const int tid = threadIdx.x;
  const int p0 = blockIdx.x * 16;
  const int k0 = blockIdx.y * G2_KC;
  const int validp = (NP - p0 < 16) ? (NP - p0) : 16;

  // stage A: wT/eT rows k0..k0+95 (rows >= NT zero-padded in ws)
  for (int idx = tid; idx < G2_KC * 16; idx += 256) {
    const int k = idx >> 4;
    const int mq = (idx & 15) * 4;
    *(float4*)&Aw[k][mq] = *(const float4*)(ws + OFF_WT + (size_t)(k0 + k) * 64 + mq);
    *(float4*)&Ae[k][mq] = *(const float4*)(ws + OFF_ET + (size_t)(k0 + k) * 64 + mq);
  }
  // stage B: (xt,Ja) interleaved [k][p-local]
  for (int idx = tid; idx < G2_KC * 4; idx += 256) {
    const int k = idx >> 2;
    const int pq = (idx & 3) * 4;
    const int t = k0 + k;
    float4 v = make_float4(0.f, 0.f, 0.f, 0.f), j = v;
    if (pq < validp && t < NT) {
      v = *(const float4*)(xt + (size_t)t * NP + p0 + pq);
      j = *(const float4*)(Ja + (size_t)t * NP + p0 + pq);
    }
    *(float4*)&Bvj[k][pq]     = make_float4(v.x, j.x, v.y, j.y);
    *(float4*)&Bvj[k][pq + 2] = make_float4(v.z, j.z, v.w, j.w);
  }
  __syncthreads();

  const int r = tid & 31;   // m-pair
  const int c = tid >> 5;   // p-pair
  float f1[2][2] = {{0.f, 0.f}, {0.f, 0.f}};  // [m][p]
  float f2[2][2] = {{0.f, 0.f}, {0.f, 0.f}};
#pragma unroll 4
  for (int k = 0; k < G2_KC; k++) {
    const float2 aw = *(const float2*)&Aw[k][2 * r];
    const float2 ae = *(const float2*)&Ae[k][2 * r];
    const float4 b  = *(const float4*)&Bvj[k][2 * c];  // (v_p, j_p, v_p1, j_p1)
    f1[0][0] = fmaf(aw.x, b.x, f1[0][0]); f1[0][1] = fmaf(aw.x, b.z, f1[0][1]);
    f1[1][0] = fmaf(aw.y, b.x, f1[1][0]); f1[1][1] = fmaf(aw.y, b.z, f1[1][1]);
    f2[0][0] = fmaf(ae.x, b.y, f2[0][0]); f2[0][1] = fmaf(ae.x, b.w, f2[0][1]);
    f2[1][0] = fmaf(ae.y, b.y, f2[1][0]); f2[1][1] = fmaf(ae.y, b.w, f2[1][1]);
  }

  const int sh = blockIdx.y & 7;
  float* b1 = ws + OFF_SH + (size_t)(sh * 2 + 0) * NP * 64;
  float* b2 = ws + OFF_SH + (size_t)(sh * 2 + 1) * NP * 64;
#pragma unroll
  for (int j = 0; j < 2; j++) {
    const int pl = 2 * c + j;
    if (pl < validp) {
      const int p = p0 + pl;
#pragma unroll
      for (int i = 0; i < 2; i++) {
        atomicAdd(b1 + (size_t)p * 64 + 2 * r + i, f1[i][j]);
        atomicAdd(b2 + (size_t)p * 64 + 2 * r + i, f2[i][j]);
      }
    }
  }
}

// ---------- kernel 4: finalize (reduce shadows, force gather, Es) ----------
__global__ __launch_bounds__(320) void k_final(const float* __restrict__ Rs,
                                               const float* __restrict__ ws,
                                               float* __restrict__ out) {
  const int m = blockIdx.x;
  const int tid = threadIdx.x;
  __shared__ float fx[NP];
  __shared__ float sR[NA * 3];
  if (tid < NA * 3) sR[tid] = Rs[m * NA * 3 + tid];
  const float sw = ws[OFF_SW + m];
  for (int p = tid; p < NP; p += 320) {
    float f1p = 0.f, f2 = 0.f;
#pragma unroll
    for (int s = 0; s < 8; s++) {
      f1p += ws[OFF_SH + ((size_t)(s * 2 + 0) * NP + p) * 64 + m];
      f2  += ws[OFF_SH + ((size_t)(s * 2 + 1) * NP + p) * 64 + m];
    }
    const float u = ws[OFF_XST + p * 64 + m];
    const float F1 = QC * (u * sw - f1p);
    fx[p] = (F1 - f2) * u * u * u;
  }
  __syncthreads();
  if (tid == 0) out[m] = ws[OFF_ES + m] / QC;  // *STD + C, STD=1, C=0
  if (tid < NA * 3) {
    const int a = tid / 3, cc = tid % 3;
    const float ra = sR[a * 3 + cc];
    float acc = 0.f;
    for (int b = 0; b < NA; b++) {
      if (b == a) continue;
      const int i = a > b ? a : b, j = a > b ? b : a;
      const int p = i * (i - 1) / 2 + j;
      acc += (sR[b * 3 + cc] - ra) * fx[p];
    }
    out[MM + m * NA * 3 + tid] = acc;
  }
}

extern "C" void kernel_launch(void* const* d_in, const int* in_sizes, int n_in,
                              void* d_out, int out_size, void* d_ws, size_t ws_size,
                              hipStream_t stream) {
  const float* Rs = (const float*)d_in[0];
  const float* xt = (const float*)d_in[1];
  const float* Ja = (const float*)d_in[2];
  float* out = (float*)d_out;
  float* ws = (float*)d_ws;

  k_pre<<<128, 256, 0, stream>>>(Rs, ws);
  k_g1<<<dim3(375, 2), 256, 0, stream>>>(xt, Ja, ws);
  k_g2<<<dim3(18, 63), 256, 0, stream>>>(xt, Ja, ws);
  k_final<<<MM, 320, 0, stream>>>(Rs, ws, out);
}